// Round 22
// baseline (855.538 us; speedup 1.0000x reference)
//
#include <hip/hip_runtime.h>

// RK4 neural-ODE: f(y) = tanh(y W1 + b1) W2 + b2;  3072 rows x 255 steps.
// One wave per row, wave-synchronous. 768x256, waves_per_eu(3,3).
//
// ROUND 26: READLANE->SCALAR-FMA y-broadcast (kill the LDS-y register block).
// Ledger: R21 = 769us but occupancy STUCK at 26% (2 waves/SIMD, 1.5-pass);
// fences/pins/attrs/scalarize all failed to cross the 170-reg line. Last
// identifiable block: LDS y-broadcast (8 hoistable yv b128 = 32 transient
// VGPRs + ybase/yrd). Key insight vs R8's failed readlane: VOP3P fma2 needed
// a VGPR splat per readlane (+2 movs); post-R16 scalar v_fma_f32 (VOP3)
// takes the readlane SGPR DIRECTLY -- zero splat cost. 32 readlanes/eval
// replace 8 reads+1 write+2 barriers and free ~36 arch regs.
// Accumulation order identical (dims 0..31, even/odd chains) => bit-identical
// => absmax must stay 0.015625.
// Predict: occupancy 26->~37% (decisive tell), dur 560-650us, VALUBusy>=85,
// VGPR ~48-64. Refute: occupancy ~26% + dur 790-860 -> register lever dead
// (5 attempts) -> revert to R21, consider MFMA-tile rewrite.

typedef float f2 __attribute__((ext_vector_type(2)));
typedef float f4 __attribute__((ext_vector_type(4)));

__device__ __forceinline__ float rl(float v, int lane) {
  return __int_as_float(__builtin_amdgcn_readlane(__float_as_int(v), lane));
}
// tanh(z) with z pre-scaled by 2*log2(e): tanh = 1 - 2/(2^z + 1)
__device__ __forceinline__ float tanh_scaled(float z) {
  float t = __builtin_amdgcn_exp2f(z);
  return fmaf(-2.0f, __builtin_amdgcn_rcpf(t + 1.0f), 1.0f);
}
// quad_perm xor-1 / xor-2 (VALU-pipe cross-lane)
__device__ __forceinline__ float dpp_xor1(float x) {
  return __int_as_float(__builtin_amdgcn_update_dpp(
      0, __float_as_int(x), 0xB1, 0xF, 0xF, true));  // [1,0,3,2]
}
__device__ __forceinline__ float dpp_xor2(float x) {
  return __int_as_float(__builtin_amdgcn_update_dpp(
      0, __float_as_int(x), 0x4E, 0xF, 0xF, true));  // [2,3,0,1]
}

#define REP32(X) \
  X(0) X(1) X(2) X(3) X(4) X(5) X(6) X(7) X(8) X(9) X(10) X(11) X(12) X(13) \
  X(14) X(15) X(16) X(17) X(18) X(19) X(20) X(21) X(22) X(23) X(24) X(25)   \
  X(26) X(27) X(28) X(29) X(30) X(31)

__global__ void __launch_bounds__(256)
__attribute__((amdgpu_waves_per_eu(3, 3)))
rk4_ode_kernel(const float* __restrict__ fp,   // [3072,32]
               const float* __restrict__ ts,   // [256]
               const float* __restrict__ W1,   // [32,128]
               const float* __restrict__ b1,   // [128]
               const float* __restrict__ W2,   // [128,32]
               const float* __restrict__ b2,   // [32]
               float* __restrict__ out) {      // [3072,256,32]
  // per-wave h buffer: 8 chunks of 16 floats at stride 20 (bank stagger)
  __shared__ float smem[4 * 160];

  const int tid = threadIdx.x;
  const int wv  = tid >> 6;
  const int p   = tid & 63;
  const int row = blockIdx.x * 4 + wv;

  const int g  = (p & 3) | ((p >> 5) << 2);   // j-group: lane bits {0,1,5}
  const int j0 = g << 4;                      // 16 j's per group
  const int d0 = p & 0x1C;                    // outputs d0|m, m=0..3

  const float C = 2.885390081777926814f;      // 2*log2(e) folded into W1/b1

  // ---- W1: lane p produces h_{2p}, h_{2p+1}; SCALAR col-pair regs ----
  const float2* W1v = reinterpret_cast<const float2*>(W1);
#define LOADW1(dd) float w1x_##dd, w1y_##dd; \
  { const float2 t_ = W1v[dd * 64 + p]; w1x_##dd = t_.x * C; w1y_##dd = t_.y * C; }
  REP32(LOADW1)
#undef LOADW1
  const float2 b1t = reinterpret_cast<const float2*>(b1)[p];
  const float b1x = b1t.x * C, b1y = b1t.y * C;

  // ---- W2: rows [j0, j0+16) for 4 outputs d0|m, SCALAR j-pair regs ----
#define LW2(m) \
  const float w2a_##m##_0 = W2[(j0 + 0)  * 32 + (d0 | m)], w2b_##m##_0 = W2[(j0 + 1)  * 32 + (d0 | m)]; \
  const float w2a_##m##_1 = W2[(j0 + 2)  * 32 + (d0 | m)], w2b_##m##_1 = W2[(j0 + 3)  * 32 + (d0 | m)]; \
  const float w2a_##m##_2 = W2[(j0 + 4)  * 32 + (d0 | m)], w2b_##m##_2 = W2[(j0 + 5)  * 32 + (d0 | m)]; \
  const float w2a_##m##_3 = W2[(j0 + 6)  * 32 + (d0 | m)], w2b_##m##_3 = W2[(j0 + 7)  * 32 + (d0 | m)]; \
  const float w2a_##m##_4 = W2[(j0 + 8)  * 32 + (d0 | m)], w2b_##m##_4 = W2[(j0 + 9)  * 32 + (d0 | m)]; \
  const float w2a_##m##_5 = W2[(j0 + 10) * 32 + (d0 | m)], w2b_##m##_5 = W2[(j0 + 11) * 32 + (d0 | m)]; \
  const float w2a_##m##_6 = W2[(j0 + 12) * 32 + (d0 | m)], w2b_##m##_6 = W2[(j0 + 13) * 32 + (d0 | m)]; \
  const float w2a_##m##_7 = W2[(j0 + 14) * 32 + (d0 | m)], w2b_##m##_7 = W2[(j0 + 15) * 32 + (d0 | m)];
  LW2(0) LW2(1) LW2(2) LW2(3)
#undef LW2
  const float b2l = b2[p & 31];

  // ---- RK4 state: lane p holds dim d = p&31 (valid on all 64 lanes) ----
  float y0   = fp[row * 32 + (p & 31)];
  float ycur = y0;
  float kacc = 0.0f;

  float* outrow = out + (size_t)row * (256 * 32);
  if (p < 32) outrow[p] = y0;

  // h LDS addressing: h_j stored at float index 20*(j>>4) + (j&15)
  float* hwbase = &smem[wv * 160];
  float* hwr    = hwbase + 20 * (p >> 3) + 2 * (p & 7);   // write f2 (j=2p,2p+1)
  const f4* hrd = reinterpret_cast<const f4*>(hwbase + 20 * g); // 4x b128 reads
  const int pairaddr = (p ^ 32) << 2;

  for (int t = 0; t < 255; ++t) {
    const float dt = ts[t + 1] - ts[t];
#pragma unroll
    for (int st = 0; st < 4; ++st) {
      // ---- phase 1: z = C*(b1 + y.W1) for cols 2p,2p+1 ----
      // y broadcast via readlane -> SGPR -> scalar v_fma_f32 (VOP3 takes the
      // SGPR directly; no splat, no LDS, no transient yv registers).
      float aex = b1x, aox = 0.0f, aey = b1y, aoy = 0.0f;
#define P1E(dd) { const float s_ = rl(ycur, dd); \
                  aex = fmaf(s_, w1x_##dd, aex); aey = fmaf(s_, w1y_##dd, aey); }
#define P1O(dd) { const float s_ = rl(ycur, dd); \
                  aox = fmaf(s_, w1x_##dd, aox); aoy = fmaf(s_, w1y_##dd, aoy); }
      P1E(0)  P1O(1)  P1E(2)  P1O(3)
      P1E(4)  P1O(5)  P1E(6)  P1O(7)
      P1E(8)  P1O(9)  P1E(10) P1O(11)
      P1E(12) P1O(13) P1E(14) P1O(15)
      P1E(16) P1O(17) P1E(18) P1O(19)
      P1E(20) P1O(21) P1E(22) P1O(23)
      P1E(24) P1O(25) P1E(26) P1O(27)
      P1E(28) P1O(29) P1E(30) P1O(31)
#undef P1E
#undef P1O
      const float ax = aex + aox;
      const float ay = aey + aoy;
      *reinterpret_cast<f2*>(hwr) = (f2){tanh_scaled(ax), tanh_scaled(ay)};
      __builtin_amdgcn_wave_barrier();          // h write before h reads

      // ---- phase 2: 16 h-floats for my j-group vs 4 output columns ----
      float accx0 = 0, accy0 = 0, accx1 = 0, accy1 = 0;
      float accx2 = 0, accy2 = 0, accx3 = 0, accy3 = 0;
      {
        const f4 r_0 = hrd[0], r_1 = hrd[1];
#define ACCA(m) accx##m = fmaf(r_0.x, w2a_##m##_0, accx##m); \
                accy##m = fmaf(r_0.y, w2b_##m##_0, accy##m); \
                accx##m = fmaf(r_0.z, w2a_##m##_1, accx##m); \
                accy##m = fmaf(r_0.w, w2b_##m##_1, accy##m); \
                accx##m = fmaf(r_1.x, w2a_##m##_2, accx##m); \
                accy##m = fmaf(r_1.y, w2b_##m##_2, accy##m); \
                accx##m = fmaf(r_1.z, w2a_##m##_3, accx##m); \
                accy##m = fmaf(r_1.w, w2b_##m##_3, accy##m);
        ACCA(0) ACCA(1) ACCA(2) ACCA(3)
#undef ACCA
      }
      __builtin_amdgcn_wave_barrier();          // live-range fence (r_2,r_3)
      {
        const f4 r_2 = hrd[2], r_3 = hrd[3];
#define ACCB(m) accx##m = fmaf(r_2.x, w2a_##m##_4, accx##m); \
                accy##m = fmaf(r_2.y, w2b_##m##_4, accy##m); \
                accx##m = fmaf(r_2.z, w2a_##m##_5, accx##m); \
                accy##m = fmaf(r_2.w, w2b_##m##_5, accy##m); \
                accx##m = fmaf(r_3.x, w2a_##m##_6, accx##m); \
                accy##m = fmaf(r_3.y, w2b_##m##_6, accy##m); \
                accx##m = fmaf(r_3.z, w2a_##m##_7, accx##m); \
                accy##m = fmaf(r_3.w, w2b_##m##_7, accy##m);
        ACCB(0) ACCB(1) ACCB(2) ACCB(3)
#undef ACCB
      }
      __builtin_amdgcn_wave_barrier();          // h reads before next h write

      // ---- combine group partials: ^1,^2 via DPP (VALU), select, then ^32 ----
      float k0 = accx0 + accy0, k1 = accx1 + accy1;
      float k2 = accx2 + accy2, k3 = accx3 + accy3;
      k0 += dpp_xor1(k0); k1 += dpp_xor1(k1); k2 += dpp_xor1(k2); k3 += dpp_xor1(k3);
      k0 += dpp_xor2(k0); k1 += dpp_xor2(k1); k2 += dpp_xor2(k2); k3 += dpp_xor2(k3);
      const float s01 = (p & 1) ? k1 : k0;
      const float s23 = (p & 1) ? k3 : k2;
      const float ks  = (p & 2) ? s23 : s01;    // my output's quad partial
      const float k = ks + b2l + __int_as_float(
          __builtin_amdgcn_ds_bpermute(pairaddr, __float_as_int(ks)));

      // ---- RK4 stage combination ----
      if (st == 0) {
        kacc = k;                   ycur = fmaf(0.5f * dt, k, y0);
      } else if (st == 1) {
        kacc = fmaf(2.0f, k, kacc); ycur = fmaf(0.5f * dt, k, y0);
      } else if (st == 2) {
        kacc = fmaf(2.0f, k, kacc); ycur = fmaf(dt, k, y0);
      } else {
        kacc = kacc + k;
        y0   = fmaf(dt * (1.0f / 6.0f), kacc, y0);
        ycur = y0;
      }
      // (no y publish: next stage readlanes ycur directly, wave-synchronous)
    }
    if (p < 32) outrow[(t + 1) * 32 + p] = y0;
  }
}

extern "C" void kernel_launch(void* const* d_in, const int* in_sizes, int n_in,
                              void* d_out, int out_size, void* d_ws, size_t ws_size,
                              hipStream_t stream) {
  const float* fp = (const float*)d_in[0];   // first_point [3,1024,32]
  const float* ts = (const float*)d_in[1];   // time_steps [256]
  const float* W1 = (const float*)d_in[2];   // [32,128]
  const float* b1 = (const float*)d_in[3];   // [128]
  const float* W2 = (const float*)d_in[4];   // [128,32]
  const float* b2 = (const float*)d_in[5];   // [32]
  float* out = (float*)d_out;                // [3,1024,256,32]

  rk4_ode_kernel<<<768, 256, 0, stream>>>(fp, ts, W1, b1, W2, b2, out);
}